// Round 6
// baseline (292.636 us; speedup 1.0000x reference)
//
#include <hip/hip_runtime.h>
#include <math.h>

#define N_NODES 50000
#define E_EDGES 800000
#define ET (E_EDGES + N_NODES)   // edges + self loops
#define IN_F 256
#define HID 128
#define HEADS1 8
#define C1 16
#define OUT_F 64
#define NEG_SLOPE 0.2f
#define NBLK ((N_NODES + 255) / 256)   // 196 scan blocks

typedef __attribute__((ext_vector_type(8))) short short8;
typedef __attribute__((ext_vector_type(4))) float float4v;
typedef __attribute__((ext_vector_type(2))) float float2v;

__device__ __forceinline__ float lrelu(float v) { return v > 0.f ? v : NEG_SLOPE * v; }

__device__ __forceinline__ unsigned short f2bf(float f) {
  union { float f; unsigned u; } v; v.f = f;
  unsigned r = v.u + 0x7FFF + ((v.u >> 16) & 1);   // RNE
  return (unsigned short)(r >> 16);
}

// unpack a dword of 2 bf16 -> packed float2 (lo, hi); both are single bit-ops,
// feeds v_pk_fma_f32 (gfx90a+ packed fp32) in the agg MAC loops
__device__ __forceinline__ float2v unpk2(unsigned dw) {
  union { unsigned u; float f; } lo, hi;
  lo.u = dw << 16;
  hi.u = dw & 0xffff0000u;
  float2v r; r.x = lo.f; r.y = hi.f;
  return r;
}

// async global->LDS, 16B per lane; global addr is PER-LANE, lds dest = uniform base + lane*16
__device__ __forceinline__ void stage16(const void* g, void* l) {
  __builtin_amdgcn_global_load_lds((const __attribute__((address_space(1))) void*)g,
                                   (__attribute__((address_space(3))) void*)l, 16, 0, 0);
}
#define WAIT_VM0()   asm volatile("s_waitcnt vmcnt(0)" ::: "memory")

// ---- fused W1+W2 transpose+cast + deg zero-init (one dispatch, 196 blocks) ----
__global__ __launch_bounds__(256) void wt_deg_kernel(const float* __restrict__ W1,
                                                     const float* __restrict__ W2,
                                                     unsigned short* __restrict__ W1t,
                                                     unsigned short* __restrict__ W2t,
                                                     int* __restrict__ deg) {
  int i = blockIdx.x * 256 + threadIdx.x;
  if (i < IN_F * HID) {
    int n = i / IN_F, k = i - n * IN_F;
    W1t[i] = f2bf(W1[k * HID + n]);
  } else {
    int j = i - IN_F * HID;
    if (j < HID * OUT_F) {
      int n = j / HID, k = j - n * HID;
      W2t[j] = f2bf(W2[k * OUT_F + n]);
    }
  }
  if (i <= N_NODES) deg[i] = 0;
}

// ---------------- GEMM1 (MFMA) + fused att1 ----------------
// v5: A path goes global->REGISTER directly. LDS = 32 KB (B only), 4 blocks/CU.
// v6: block mapping puts the two col-halves of one row-group 8 bids apart
// (ch=(bid>>3)&1) so they land on the SAME XCD (round-robin period 8) and the
// second half hits x rows in that XCD's L2 -> x fetched once, not twice.
__global__ __launch_bounds__(256, 4) void gemm1_mfma_kernel(const float* __restrict__ x,
                                                            const unsigned short* __restrict__ W1t,
                                                            const float* __restrict__ att_src,
                                                            const float* __restrict__ att_dst,
                                                            unsigned short* __restrict__ h1bf,
                                                            float* __restrict__ a_s,
                                                            float* __restrict__ a_d) {
  __shared__ unsigned short Bls[64 * 256];   // 32 KB: [col][k], chunk j stored at j^(col&31)
  const int bid = blockIdx.x;                // grid padded to 1568 = 98*16 (bijective map)
  const int ch = (bid >> 3) & 1;
  const int rb = (bid & 7) | ((bid >> 4) << 3);   // rb in [0,784); rb>=782 exits on m0 guard
  const int wv = threadIdx.x >> 6;
  const int lane = threadIdx.x & 63;
  const int wave = rb * 4 + wv;
  const int m0 = wave * 16;
  const int lm = lane & 15;
  const int quad = lane >> 4;
  const int c0 = ch * 64;

  // ---- stage this half's B (64 cols x 256 k) into LDS, swizzled ----
  {
    const int lrow = lane >> 5;              // which of 2 cols per instr
    const int jp = lane & 31;                // stored 16B-chunk position
#pragma unroll
    for (int s8 = 0; s8 < 8; ++s8) {
      int s = wv * 8 + s8;                   // staging instr 0..31
      int cl = 2 * s + lrow;                 // local col 0..63
      int j = jp ^ (cl & 31);                // global chunk fetched into slot jp
      stage16(W1t + ((size_t)(c0 + cl) * IN_F + j * 8),
              (unsigned short*)Bls + (size_t)s * 512);
    }
  }
  WAIT_VM0();
  __syncthreads();                           // only barrier in the kernel
  if (m0 >= N_NODES) return;                 // idle waves exit AFTER barrier

  // ---- A: direct global->reg, depth-3 prefetch (fully unrolled => renames) ----
  const float* ap = x + (size_t)(m0 + lm) * IN_F + quad * 8;
  float4 f0[3], f1[3];
#pragma unroll
  for (int t = 0; t < 3; ++t) {
    f0[t] = *(const float4*)(ap + t * 32);
    f1[t] = *(const float4*)(ap + t * 32 + 4);
  }

  float4v acc[4];
#pragma unroll
  for (int nt = 0; nt < 4; ++nt) acc[nt] = (float4v){0.f, 0.f, 0.f, 0.f};

#pragma unroll
  for (int kk = 0; kk < 8; ++kk) {
    float4 a0 = f0[0], a1 = f1[0];
    f0[0] = f0[1]; f0[1] = f0[2];
    f1[0] = f1[1]; f1[1] = f1[2];
    if (kk < 5) {
      f0[2] = *(const float4*)(ap + (kk + 3) * 32);
      f1[2] = *(const float4*)(ap + (kk + 3) * 32 + 4);
    }
    short8 a;
    a[0] = f2bf(a0.x); a[1] = f2bf(a0.y); a[2] = f2bf(a0.z); a[3] = f2bf(a0.w);
    a[4] = f2bf(a1.x); a[5] = f2bf(a1.y); a[6] = f2bf(a1.z); a[7] = f2bf(a1.w);
#pragma unroll
    for (int nt = 0; nt < 4; ++nt) {
      int c = nt * 16 + lm;                  // local col
      short8 b = *(const short8*)&Bls[(size_t)c * IN_F + (size_t)((kk * 4 + quad) ^ (c & 31)) * 8];
      acc[nt] = __builtin_amdgcn_mfma_f32_16x16x32_bf16(a, b, acc[nt], 0, 0, 0);
    }
  }

#pragma unroll
  for (int nt = 0; nt < 4; ++nt) {
#pragma unroll
    for (int r = 0; r < 4; ++r) {
      int row = m0 + quad * 4 + r;
      h1bf[(size_t)row * HID + c0 + nt * 16 + lm] = f2bf(acc[nt][r]);
    }
  }

  // ---- fused att1: this wave owns heads ch*4+nt ----
  float asv[4], adv[4];
#pragma unroll
  for (int nt = 0; nt < 4; ++nt) {
    asv[nt] = att_src[c0 + nt * 16 + lm];
    adv[nt] = att_dst[c0 + nt * 16 + lm];
  }
#pragma unroll
  for (int r = 0; r < 4; ++r) {
    int row = m0 + quad * 4 + r;
    float s[4], d[4];
#pragma unroll
    for (int nt = 0; nt < 4; ++nt) { s[nt] = acc[nt][r] * asv[nt]; d[nt] = acc[nt][r] * adv[nt]; }
#pragma unroll
    for (int m = 1; m < 16; m <<= 1) {
#pragma unroll
      for (int nt = 0; nt < 4; ++nt) { s[nt] += __shfl_xor(s[nt], m); d[nt] += __shfl_xor(d[nt], m); }
    }
    if (lm == 0) {
#pragma unroll
      for (int nt = 0; nt < 4; ++nt) {
        a_s[(size_t)row * HEADS1 + ch * 4 + nt] = s[nt];
        a_d[(size_t)row * HEADS1 + ch * 4 + nt] = d[nt];
      }
    }
  }
}

// ---------------- GEMM2 (MFMA) + fused att2 ----------------
// v5: zero LDS. A (out1bf, already bf16) read per-lane as short8 directly;
// W2t frags direct from global (16 KB, L2-resident).
__global__ __launch_bounds__(256) void gemm2_mfma_kernel(const unsigned short* __restrict__ in,
                                                         const unsigned short* __restrict__ W2t,
                                                         const float* __restrict__ att_src,
                                                         const float* __restrict__ att_dst,
                                                         unsigned short* __restrict__ h2bf,
                                                         float* __restrict__ a_s,
                                                         float* __restrict__ a_d) {
  const int wv = threadIdx.x >> 6;
  const int wave = blockIdx.x * 4 + wv;
  const int lane = threadIdx.x & 63;
  const int m0 = wave * 16;
  if (m0 >= N_NODES) return;
  const int lm = lane & 15;
  const int quad = lane >> 4;

  const short8* ga = (const short8*)(in + (size_t)(m0 + lm) * HID + quad * 8);

  float4v acc[4];
#pragma unroll
  for (int nt = 0; nt < 4; ++nt) acc[nt] = (float4v){0.f, 0.f, 0.f, 0.f};

#pragma unroll
  for (int kk = 0; kk < 4; ++kk) {                // K = 4 x 32
    short8 a = ga[kk * 4];                        // kk*32 shorts = 4 short8
#pragma unroll
    for (int nt = 0; nt < 4; ++nt) {
      short8 b = *(const short8*)&W2t[(size_t)(nt * 16 + lm) * HID + kk * 32 + quad * 8];
      acc[nt] = __builtin_amdgcn_mfma_f32_16x16x32_bf16(a, b, acc[nt], 0, 0, 0);
    }
  }

#pragma unroll
  for (int nt = 0; nt < 4; ++nt) {
#pragma unroll
    for (int r = 0; r < 4; ++r) {
      int row = m0 + quad * 4 + r;
      h2bf[(size_t)row * OUT_F + nt * 16 + lm] = f2bf(acc[nt][r]);
    }
  }

  // ---- fused att2: single head over 64 cols ----
  float as0 = att_src[lm], as1v = att_src[16 + lm], as2v = att_src[32 + lm], as3 = att_src[48 + lm];
  float ad0 = att_dst[lm], ad1v = att_dst[16 + lm], ad2v = att_dst[32 + lm], ad3 = att_dst[48 + lm];
#pragma unroll
  for (int r = 0; r < 4; ++r) {
    int row = m0 + quad * 4 + r;
    float s = acc[0][r] * as0 + acc[1][r] * as1v + acc[2][r] * as2v + acc[3][r] * as3;
    float d = acc[0][r] * ad0 + acc[1][r] * ad1v + acc[2][r] * ad2v + acc[3][r] * ad3;
#pragma unroll
    for (int m = 1; m < 16; m <<= 1) { s += __shfl_xor(s, m); d += __shfl_xor(d, m); }
    if (lm == 0) { a_s[row] = s; a_d[row] = d; }
  }
}

// ---------------- CSR construction (v6: single-pass, 1 edge/thread) ------------
// Replaces the 8x dst-range-partitioned versions: those streamed the full dst
// array 8x per kernel (27 MB vs 3.4 MB) for atomic locality that deg/cursor
// (200 KB, L2-resident) never needed.
__global__ __launch_bounds__(256) void deg_kernel(const int* __restrict__ ei,
                                                  int* __restrict__ deg) {
  int e = blockIdx.x * 256 + threadIdx.x;
  if (e < ET) {
    int d = (e < E_EDGES) ? ei[E_EDGES + e] : (e - E_EDGES);
    atomicAdd(&deg[d], 1);
  }
}

__global__ __launch_bounds__(256) void scatter_kernel(const int* __restrict__ ei,
                                                      int* __restrict__ cursor,
                                                      int* __restrict__ csr_src) {
  int e = blockIdx.x * 256 + threadIdx.x;
  if (e < ET) {
    int d = (e < E_EDGES) ? ei[E_EDGES + e] : (e - E_EDGES);
    int s = (e < E_EDGES) ? ei[e] : d;
    int pos = atomicAdd(&cursor[d], 1);
    csr_src[pos] = s;
  }
}

__global__ __launch_bounds__(256) void scan1_kernel(const int* __restrict__ deg,
                                                    int* __restrict__ exq,
                                                    int* __restrict__ bsum) {
  __shared__ int sh[256];
  const int t = threadIdx.x;
  const int idx = blockIdx.x * 256 + t;
  int v = (idx < N_NODES) ? deg[idx] : 0;
  sh[t] = v;
  __syncthreads();
  for (int off = 1; off < 256; off <<= 1) {
    int u = (t >= off) ? sh[t - off] : 0;
    __syncthreads();
    sh[t] += u;
    __syncthreads();
  }
  if (idx < N_NODES) exq[idx] = sh[t] - v;
  if (t == 255) bsum[blockIdx.x] = sh[t];
}

__global__ __launch_bounds__(256) void scan2_kernel(const int* __restrict__ bsum,
                                                    int* __restrict__ boff) {
  __shared__ int sh[256];
  const int t = threadIdx.x;
  int v = (t < NBLK) ? bsum[t] : 0;
  sh[t] = v;
  __syncthreads();
  for (int off = 1; off < 256; off <<= 1) {
    int u = (t >= off) ? sh[t - off] : 0;
    __syncthreads();
    sh[t] += u;
    __syncthreads();
  }
  if (t < NBLK) boff[t] = sh[t] - v;
}

__global__ __launch_bounds__(256) void scan3_kernel(const int* __restrict__ exq,
                                                    const int* __restrict__ boff,
                                                    int* __restrict__ rowptr,
                                                    int* __restrict__ cursor) {
  const int idx = blockIdx.x * 256 + threadIdx.x;
  if (idx < N_NODES) {
    int r = exq[idx] + boff[blockIdx.x];
    rowptr[idx] = r;
    cursor[idx] = r;
  }
  if (idx == 0) rowptr[N_NODES] = ET;
}

// ---------------- agg1: wave/dst; 16-lane×16B row gathers (4 edges/instr) -------
// v4: one vector load prefetches the whole neighbor list (lane l holds
// csr_src[start+l], clamped); per-round indices via __shfl. Rounds unrolled with
// wave-uniform deg guards so all gathers of a wave issue back-to-back.
__global__ __launch_bounds__(256) void agg1_csr_kernel(const int* __restrict__ rowptr,
                                                       const int* __restrict__ csr_src,
                                                       const float* __restrict__ a_s,
                                                       const float* __restrict__ a_d,
                                                       const unsigned short* __restrict__ h1bf,
                                                       const float* __restrict__ b1,
                                                       unsigned short* __restrict__ out1bf) {
  int wid = (blockIdx.x * 256 + threadIdx.x) >> 6;
  int lane = threadIdx.x & 63;
  if (wid >= N_NODES) return;
  const int fl = lane & 15;
  const int g  = lane >> 4;
  const int myh = fl >> 1;
  const float adn = a_d[(unsigned)(wid * HEADS1 + myh)];
  const int start = rowptr[wid], end = rowptr[wid + 1];
  const int deg = end - start;                 // >= 1 (self loop)
  // prefetch up to 64 edge indices, one per lane (clamped to start = valid node)
  int el = start + lane;
  int sall = csr_src[el < end ? el : start];
  float2v acc2[4];                  // feats fl*8 + {2d, 2d+1}
#pragma unroll
  for (int d = 0; d < 4; ++d) acc2[d] = (float2v){0.f, 0.f};
  float wsum = 0.f;

#define AGG1_ROUND(t)                                                          \
  {                                                                            \
    int i0 = 8 * (t) + g, i1 = 8 * (t) + 4 + g;                                \
    int s0 = __shfl(sall, i0);                                                 \
    int s1 = __shfl(sall, i1);                                                 \
    bool v0 = i0 < deg, v1 = i1 < deg;                                         \
    float l0 = a_s[(unsigned)(s0 * HEADS1 + myh)];                             \
    float l1 = a_s[(unsigned)(s1 * HEADS1 + myh)];                             \
    uint4 r0 = *(const uint4*)&h1bf[(unsigned)(s0 * HID + fl * 8)];            \
    uint4 r1 = *(const uint4*)&h1bf[(unsigned)(s1 * HID + fl * 8)];            \
    float w0 = v0 ? __expf(lrelu(l0 + adn)) : 0.f;                             \
    float w1 = v1 ? __expf(lrelu(l1 + adn)) : 0.f;                             \
    float2v w0v = {w0, w0}, w1v = {w1, w1};                                    \
    acc2[0] += w0v * unpk2(r0.x);  acc2[0] += w1v * unpk2(r1.x);               \
    acc2[1] += w0v * unpk2(r0.y);  acc2[1] += w1v * unpk2(r1.y);               \
    acc2[2] += w0v * unpk2(r0.z);  acc2[2] += w1v * unpk2(r1.z);               \
    acc2[3] += w0v * unpk2(r0.w);  acc2[3] += w1v * unpk2(r1.w);               \
    wsum += w0 + w1;                                                           \
  }

  AGG1_ROUND(0)
  AGG1_ROUND(1)
  if (deg > 16) {                      // wave-uniform branch
    AGG1_ROUND(2)
    AGG1_ROUND(3)
  }
#undef AGG1_ROUND
  if (deg > 32) {                      // rare tail (P[deg>32] ~ 1e-4)
    for (int i = start + 32; i < end; i += 8) {
      int e0 = i + g, e1 = i + 4 + g;
      bool v0 = e0 < end, v1 = e1 < end;
      int s0 = csr_src[v0 ? e0 : start];
      int s1 = csr_src[v1 ? e1 : start];
      float l0 = a_s[(unsigned)(s0 * HEADS1 + myh)];
      float l1 = a_s[(unsigned)(s1 * HEADS1 + myh)];
      uint4 r0 = *(const uint4*)&h1bf[(unsigned)(s0 * HID + fl * 8)];
      uint4 r1 = *(const uint4*)&h1bf[(unsigned)(s1 * HID + fl * 8)];
      float w0 = v0 ? __expf(lrelu(l0 + adn)) : 0.f;
      float w1 = v1 ? __expf(lrelu(l1 + adn)) : 0.f;
      float2v w0v = {w0, w0}, w1v = {w1, w1};
      acc2[0] += w0v * unpk2(r0.x);  acc2[0] += w1v * unpk2(r1.x);
      acc2[1] += w0v * unpk2(r0.y);  acc2[1] += w1v * unpk2(r1.y);
      acc2[2] += w0v * unpk2(r0.z);  acc2[2] += w1v * unpk2(r1.z);
      acc2[3] += w0v * unpk2(r0.w);  acc2[3] += w1v * unpk2(r1.w);
      wsum += w0 + w1;
    }
  }

#pragma unroll
  for (int d = 0; d < 4; ++d) {
    float ax = acc2[d].x, ay = acc2[d].y;
    ax += __shfl_xor(ax, 16); ax += __shfl_xor(ax, 32);
    ay += __shfl_xor(ay, 16); ay += __shfl_xor(ay, 32);
    acc2[d].x = ax; acc2[d].y = ay;
  }
  wsum += __shfl_xor(wsum, 16);
  wsum += __shfl_xor(wsum, 32);

  // ---- distributed epilogue: lane (fl,g) finalizes feats fl*8+g*2 .. +1 ----
  float inv = 1.f / (wsum + 1e-16f);
  float2v ee = (g & 2) ? ((g & 1) ? acc2[3] : acc2[2]) : ((g & 1) ? acc2[1] : acc2[0]);
  float2 bb = *(const float2*)&b1[fl * 8 + g * 2];
  float v0 = ee.x * inv + bb.x;
  float v1 = ee.y * inv + bb.y;
  v0 = v0 > 0.f ? v0 : __expf(v0) - 1.f;   // ELU; bf16-quantized below
  v1 = v1 > 0.f ? v1 : __expf(v1) - 1.f;
  unsigned pk = (unsigned)f2bf(v0) | ((unsigned)f2bf(v1) << 16);
  ((unsigned*)&out1bf[(size_t)wid * HID])[fl * 4 + g] = pk;   // 64-lane 256B row
}

// ---------------- agg2: wave/dst; 8-lane×16B row gathers (8 edges/instr) --------
__global__ __launch_bounds__(256) void agg2_csr_kernel(const int* __restrict__ rowptr,
                                                       const int* __restrict__ csr_src,
                                                       const float* __restrict__ a_s,
                                                       const float* __restrict__ a_d,
                                                       const unsigned short* __restrict__ h2bf,
                                                       const float* __restrict__ b2,
                                                       float* __restrict__ out) {
  int wid = (blockIdx.x * 256 + threadIdx.x) >> 6;
  int lane = threadIdx.x & 63;
  if (wid >= N_NODES) return;
  const int fl = lane & 7;       // owns feats [8*fl, 8*fl+8)
  const int g  = lane >> 3;      // edge group 0..7
  const float adn = a_d[wid];
  const int start = rowptr[wid], end = rowptr[wid + 1];
  const int deg = end - start;
  int el = start + lane;
  int sall = csr_src[el < end ? el : start];
  float2v acc2[4];               // feats fl*8 + {2d, 2d+1}
#pragma unroll
  for (int d = 0; d < 4; ++d) acc2[d] = (float2v){0.f, 0.f};
  float wsum = 0.f;

#define AGG2_ROUND(t)                                                          \
  {                                                                            \
    int i0 = 16 * (t) + g, i1 = 16 * (t) + 8 + g;                              \
    int s0 = __shfl(sall, i0);                                                 \
    int s1 = __shfl(sall, i1);                                                 \
    bool v0 = i0 < deg, v1 = i1 < deg;                                         \
    float l0 = a_s[s0];                                                        \
    float l1 = a_s[s1];                                                        \
    uint4 r0 = *(const uint4*)&h2bf[(unsigned)(s0 * OUT_F + fl * 8)];          \
    uint4 r1 = *(const uint4*)&h2bf[(unsigned)(s1 * OUT_F + fl * 8)];          \
    float w0 = v0 ? __expf(lrelu(l0 + adn)) : 0.f;                             \
    float w1 = v1 ? __expf(lrelu(l1 + adn)) : 0.f;                             \
    float2v w0v = {w0, w0}, w1v = {w1, w1};                                    \
    acc2[0] += w0v * unpk2(r0.x);  acc2[0] += w1v * unpk2(r1.x);               \
    acc2[1] += w0v * unpk2(r0.y);  acc2[1] += w1v * unpk2(r1.y);               \
    acc2[2] += w0v * unpk2(r0.z);  acc2[2] += w1v * unpk2(r1.z);               \
    acc2[3] += w0v * unpk2(r0.w);  acc2[3] += w1v * unpk2(r1.w);               \
    wsum += w0 + w1;                                                           \
  }

  AGG2_ROUND(0)
  if (deg > 16) {                      // wave-uniform branch
    AGG2_ROUND(1)
  }
#undef AGG2_ROUND
  if (deg > 32) {                      // rare tail
    for (int i = start + 32; i < end; i += 16) {
      int e0 = i + g, e1 = i + 8 + g;
      bool v0 = e0 < end, v1 = e1 < end;
      int s0 = csr_src[v0 ? e0 : start];
      int s1 = csr_src[v1 ? e1 : start];
      float l0 = a_s[s0];
      float l1 = a_s[s1];
      uint4 r0 = *(const uint4*)&h2bf[(unsigned)(s0 * OUT_F + fl * 8)];
      uint4 r1 = *(const uint4*)&h2bf[(unsigned)(s1 * OUT_F + fl * 8)];
      float w0 = v0 ? __expf(lrelu(l0 + adn)) : 0.f;
      float w1 = v1 ? __expf(lrelu(l1 + adn)) : 0.f;
      float2v w0v = {w0, w0}, w1v = {w1, w1};
      acc2[0] += w0v * unpk2(r0.x);  acc2[0] += w1v * unpk2(r1.x);
      acc2[1] += w0v * unpk2(r0.y);  acc2[1] += w1v * unpk2(r1.y);
      acc2[2] += w0v * unpk2(r0.z);  acc2[2] += w1v * unpk2(r1.z);
      acc2[3] += w0v * unpk2(r0.w);  acc2[3] += w1v * unpk2(r1.w);
      wsum += w0 + w1;
    }
  }

#pragma unroll
  for (int d = 0; d < 4; ++d) {
    float ax = acc2[d].x, ay = acc2[d].y;
    ax += __shfl_xor(ax, 8); ax += __shfl_xor(ax, 16); ax += __shfl_xor(ax, 32);
    ay += __shfl_xor(ay, 8); ay += __shfl_xor(ay, 16); ay += __shfl_xor(ay, 32);
    acc2[d].x = ax; acc2[d].y = ay;
  }
  wsum += __shfl_xor(wsum, 8);
  wsum += __shfl_xor(wsum, 16);
  wsum += __shfl_xor(wsum, 32);

  float inv = 1.f / (wsum + 1e-16f);
  float4 blo = *(const float4*)&b2[fl * 8];
  float4 bhi = *(const float4*)&b2[fl * 8 + 4];
  float vv[8];
  vv[0] = acc2[0].x * inv + blo.x; vv[1] = acc2[0].y * inv + blo.y;
  vv[2] = acc2[1].x * inv + blo.z; vv[3] = acc2[1].y * inv + blo.w;
  vv[4] = acc2[2].x * inv + bhi.x; vv[5] = acc2[2].y * inv + bhi.y;
  vv[6] = acc2[3].x * inv + bhi.z; vv[7] = acc2[3].y * inv + bhi.w;
  float m = vv[0];
#pragma unroll
  for (int k = 1; k < 8; ++k) m = fmaxf(m, vv[k]);
#pragma unroll
  for (int msk = 1; msk < 8; msk <<= 1) m = fmaxf(m, __shfl_xor(m, msk));
  float sm = 0.f;
#pragma unroll
  for (int k = 0; k < 8; ++k) sm += __expf(vv[k] - m);
#pragma unroll
  for (int msk = 1; msk < 8; msk <<= 1) sm += __shfl_xor(sm, msk);
  float lse = m + __logf(sm);
  if (g == 0) {
    float4 o0 = make_float4(vv[0] - lse, vv[1] - lse, vv[2] - lse, vv[3] - lse);
    float4 o1 = make_float4(vv[4] - lse, vv[5] - lse, vv[6] - lse, vv[7] - lse);
    *(float4*)&out[(size_t)wid * OUT_F + fl * 8]     = o0;
    *(float4*)&out[(size_t)wid * OUT_F + fl * 8 + 4] = o1;
  }
}

extern "C" void kernel_launch(void* const* d_in, const int* in_sizes, int n_in,
                              void* d_out, int out_size, void* d_ws, size_t ws_size,
                              hipStream_t stream) {
  const float* x   = (const float*)d_in[0];
  const int* ei    = (const int*)d_in[1];
  const float* W1  = (const float*)d_in[2];
  const float* as1 = (const float*)d_in[3];
  const float* ad1 = (const float*)d_in[4];
  const float* b1  = (const float*)d_in[5];
  const float* W2  = (const float*)d_in[6];
  const float* as2 = (const float*)d_in[7];
  const float* ad2 = (const float*)d_in[8];
  const float* b2  = (const float*)d_in[9];
  float* out = (float*)d_out;

  float* ws = (float*)d_ws;
  float* a_s1   = ws;  ws += (size_t)N_NODES * HEADS1;
  float* a_d1   = ws;  ws += (size_t)N_NODES * HEADS1;
  float* a_s2   = ws;  ws += (size_t)N_NODES;
  float* a_d2   = ws;  ws += (size_t)N_NODES;
  unsigned short* h1bf   = (unsigned short*)ws;  ws += (size_t)N_NODES * HID / 2;
  unsigned short* out1bf = (unsigned short*)ws;  ws += (size_t)N_NODES * HID / 2;
  unsigned short* h2bf   = (unsigned short*)ws;  ws += (size_t)N_NODES * OUT_F / 2;
  unsigned short* W1t = (unsigned short*)ws;  ws += (IN_F * HID) / 2;
  unsigned short* W2t = (unsigned short*)ws;  ws += (HID * OUT_F) / 2;
  int* deg      = (int*)ws;  ws += (N_NODES + 1);
  int* rowptr   = (int*)ws;  ws += (N_NODES + 1);
  int* cursor   = (int*)ws;  ws += N_NODES;
  int* csr_src  = (int*)ws;  ws += ET;
  int* exq      = (int*)ws;  ws += N_NODES;
  int* bsum     = (int*)ws;  ws += NBLK;
  int* boff     = (int*)ws;  ws += NBLK;

  // ---- weight transpose+cast + deg zero-init (one dispatch) ----
  wt_deg_kernel<<<dim3(NBLK), dim3(256), 0, stream>>>(W1, W2, W1t, W2t, deg);

  // ---- CSR build (single-pass deg/scatter, 1 edge/thread) ----
  deg_kernel<<<dim3((ET + 255) / 256), dim3(256), 0, stream>>>(ei, deg);
  scan1_kernel<<<dim3(NBLK), dim3(256), 0, stream>>>(deg, exq, bsum);
  scan2_kernel<<<dim3(1), dim3(256), 0, stream>>>(bsum, boff);
  scan3_kernel<<<dim3(NBLK), dim3(256), 0, stream>>>(exq, boff, rowptr, cursor);
  scatter_kernel<<<dim3((ET + 255) / 256), dim3(256), 0, stream>>>(ei, cursor, csr_src);

  // ---- layer 1 ----
  gemm1_mfma_kernel<<<dim3(1568), dim3(256), 0, stream>>>(x, W1t, as1, ad1, h1bf, a_s1, a_d1);
  agg1_csr_kernel<<<dim3((N_NODES + 3) / 4), dim3(256), 0, stream>>>(rowptr, csr_src, a_s1, a_d1, h1bf, b1, out1bf);

  // ---- layer 2 ----
  gemm2_mfma_kernel<<<dim3((N_NODES + 63) / 64), dim3(256), 0, stream>>>(out1bf, W2t, as2, ad2, h2bf, a_s2, a_d2);
  agg2_csr_kernel<<<dim3((N_NODES + 3) / 4), dim3(256), 0, stream>>>(rowptr, csr_src, a_s2, a_d2, h2bf, b2, out);
}

// Round 7
// 272.714 us; speedup vs baseline: 1.0731x; 1.0731x over previous
//
#include <hip/hip_runtime.h>
#include <math.h>

#define N_NODES 50000
#define E_EDGES 800000
#define ET (E_EDGES + N_NODES)   // edges + self loops
#define IN_F 256
#define HID 128
#define HEADS1 8
#define C1 16
#define OUT_F 64
#define NEG_SLOPE 0.2f
#define NBLK ((N_NODES + 255) / 256)   // 196 scan blocks
#define NRANGE 8
#define RSPAN ((N_NODES + NRANGE - 1) / NRANGE)   // 6250
#define BPG 256                                    // blocks per range-group

typedef __attribute__((ext_vector_type(8))) short short8;
typedef __attribute__((ext_vector_type(4))) float float4v;
typedef __attribute__((ext_vector_type(2))) float float2v;

__device__ __forceinline__ float lrelu(float v) { return v > 0.f ? v : NEG_SLOPE * v; }

__device__ __forceinline__ unsigned short f2bf(float f) {
  union { float f; unsigned u; } v; v.f = f;
  unsigned r = v.u + 0x7FFF + ((v.u >> 16) & 1);   // RNE
  return (unsigned short)(r >> 16);
}

// unpack a dword of 2 bf16 -> packed float2 (lo, hi); both are single bit-ops,
// feeds v_pk_fma_f32 (gfx90a+ packed fp32) in the agg MAC loops
__device__ __forceinline__ float2v unpk2(unsigned dw) {
  union { unsigned u; float f; } lo, hi;
  lo.u = dw << 16;
  hi.u = dw & 0xffff0000u;
  float2v r; r.x = lo.f; r.y = hi.f;
  return r;
}

// async global->LDS, 16B per lane; global addr is PER-LANE, lds dest = uniform base + lane*16
__device__ __forceinline__ void stage16(const void* g, void* l) {
  __builtin_amdgcn_global_load_lds((const __attribute__((address_space(1))) void*)g,
                                   (__attribute__((address_space(3))) void*)l, 16, 0, 0);
}
#define WAIT_VM0()   asm volatile("s_waitcnt vmcnt(0)" ::: "memory")

// ---- fused W1+W2 transpose+cast + deg zero-init (one dispatch, 196 blocks) ----
__global__ __launch_bounds__(256) void wt_deg_kernel(const float* __restrict__ W1,
                                                     const float* __restrict__ W2,
                                                     unsigned short* __restrict__ W1t,
                                                     unsigned short* __restrict__ W2t,
                                                     int* __restrict__ deg) {
  int i = blockIdx.x * 256 + threadIdx.x;
  if (i < IN_F * HID) {
    int n = i / IN_F, k = i - n * IN_F;
    W1t[i] = f2bf(W1[k * HID + n]);
  } else {
    int j = i - IN_F * HID;
    if (j < HID * OUT_F) {
      int n = j / HID, k = j - n * HID;
      W2t[j] = f2bf(W2[k * OUT_F + n]);
    }
  }
  if (i <= N_NODES) deg[i] = 0;
}

// ---------------- GEMM1 (MFMA) + fused att1 ----------------
// v5: A path goes global->REGISTER directly. LDS = 32 KB (B only), 4 blocks/CU.
// v6: block mapping puts the two col-halves of one row-group 8 bids apart
// (ch=(bid>>3)&1) so they land on the SAME XCD (round-robin period 8) and the
// second half hits x rows in that XCD's L2 -> x fetched once, not twice.
__global__ __launch_bounds__(256, 4) void gemm1_mfma_kernel(const float* __restrict__ x,
                                                            const unsigned short* __restrict__ W1t,
                                                            const float* __restrict__ att_src,
                                                            const float* __restrict__ att_dst,
                                                            unsigned short* __restrict__ h1bf,
                                                            float* __restrict__ a_s,
                                                            float* __restrict__ a_d) {
  __shared__ unsigned short Bls[64 * 256];   // 32 KB: [col][k], chunk j stored at j^(col&31)
  const int bid = blockIdx.x;                // grid padded to 1568 = 98*16 (bijective map)
  const int ch = (bid >> 3) & 1;
  const int rb = (bid & 7) | ((bid >> 4) << 3);   // rb in [0,784); rb>=782 exits on m0 guard
  const int wv = threadIdx.x >> 6;
  const int lane = threadIdx.x & 63;
  const int wave = rb * 4 + wv;
  const int m0 = wave * 16;
  const int lm = lane & 15;
  const int quad = lane >> 4;
  const int c0 = ch * 64;

  // ---- stage this half's B (64 cols x 256 k) into LDS, swizzled ----
  {
    const int lrow = lane >> 5;              // which of 2 cols per instr
    const int jp = lane & 31;                // stored 16B-chunk position
#pragma unroll
    for (int s8 = 0; s8 < 8; ++s8) {
      int s = wv * 8 + s8;                   // staging instr 0..31
      int cl = 2 * s + lrow;                 // local col 0..63
      int j = jp ^ (cl & 31);                // global chunk fetched into slot jp
      stage16(W1t + ((size_t)(c0 + cl) * IN_F + j * 8),
              (unsigned short*)Bls + (size_t)s * 512);
    }
  }
  WAIT_VM0();
  __syncthreads();                           // only barrier in the kernel
  if (m0 >= N_NODES) return;                 // idle waves exit AFTER barrier

  // ---- A: direct global->reg, depth-3 prefetch (fully unrolled => renames) ----
  const float* ap = x + (size_t)(m0 + lm) * IN_F + quad * 8;
  float4 f0[3], f1[3];
#pragma unroll
  for (int t = 0; t < 3; ++t) {
    f0[t] = *(const float4*)(ap + t * 32);
    f1[t] = *(const float4*)(ap + t * 32 + 4);
  }

  float4v acc[4];
#pragma unroll
  for (int nt = 0; nt < 4; ++nt) acc[nt] = (float4v){0.f, 0.f, 0.f, 0.f};

#pragma unroll
  for (int kk = 0; kk < 8; ++kk) {
    float4 a0 = f0[0], a1 = f1[0];
    f0[0] = f0[1]; f0[1] = f0[2];
    f1[0] = f1[1]; f1[1] = f1[2];
    if (kk < 5) {
      f0[2] = *(const float4*)(ap + (kk + 3) * 32);
      f1[2] = *(const float4*)(ap + (kk + 3) * 32 + 4);
    }
    short8 a;
    a[0] = f2bf(a0.x); a[1] = f2bf(a0.y); a[2] = f2bf(a0.z); a[3] = f2bf(a0.w);
    a[4] = f2bf(a1.x); a[5] = f2bf(a1.y); a[6] = f2bf(a1.z); a[7] = f2bf(a1.w);
#pragma unroll
    for (int nt = 0; nt < 4; ++nt) {
      int c = nt * 16 + lm;                  // local col
      short8 b = *(const short8*)&Bls[(size_t)c * IN_F + (size_t)((kk * 4 + quad) ^ (c & 31)) * 8];
      acc[nt] = __builtin_amdgcn_mfma_f32_16x16x32_bf16(a, b, acc[nt], 0, 0, 0);
    }
  }

#pragma unroll
  for (int nt = 0; nt < 4; ++nt) {
#pragma unroll
    for (int r = 0; r < 4; ++r) {
      int row = m0 + quad * 4 + r;
      h1bf[(size_t)row * HID + c0 + nt * 16 + lm] = f2bf(acc[nt][r]);
    }
  }

  // ---- fused att1: this wave owns heads ch*4+nt ----
  float asv[4], adv[4];
#pragma unroll
  for (int nt = 0; nt < 4; ++nt) {
    asv[nt] = att_src[c0 + nt * 16 + lm];
    adv[nt] = att_dst[c0 + nt * 16 + lm];
  }
#pragma unroll
  for (int r = 0; r < 4; ++r) {
    int row = m0 + quad * 4 + r;
    float s[4], d[4];
#pragma unroll
    for (int nt = 0; nt < 4; ++nt) { s[nt] = acc[nt][r] * asv[nt]; d[nt] = acc[nt][r] * adv[nt]; }
#pragma unroll
    for (int m = 1; m < 16; m <<= 1) {
#pragma unroll
      for (int nt = 0; nt < 4; ++nt) { s[nt] += __shfl_xor(s[nt], m); d[nt] += __shfl_xor(d[nt], m); }
    }
    if (lm == 0) {
#pragma unroll
      for (int nt = 0; nt < 4; ++nt) {
        a_s[(size_t)row * HEADS1 + ch * 4 + nt] = s[nt];
        a_d[(size_t)row * HEADS1 + ch * 4 + nt] = d[nt];
      }
    }
  }
}

// ---------------- GEMM2 (MFMA) + fused att2 ----------------
// v5: zero LDS. A (out1bf, already bf16) read per-lane as short8 directly;
// W2t frags direct from global (16 KB, L2-resident).
__global__ __launch_bounds__(256) void gemm2_mfma_kernel(const unsigned short* __restrict__ in,
                                                         const unsigned short* __restrict__ W2t,
                                                         const float* __restrict__ att_src,
                                                         const float* __restrict__ att_dst,
                                                         unsigned short* __restrict__ h2bf,
                                                         float* __restrict__ a_s,
                                                         float* __restrict__ a_d) {
  const int wv = threadIdx.x >> 6;
  const int wave = blockIdx.x * 4 + wv;
  const int lane = threadIdx.x & 63;
  const int m0 = wave * 16;
  if (m0 >= N_NODES) return;
  const int lm = lane & 15;
  const int quad = lane >> 4;

  const short8* ga = (const short8*)(in + (size_t)(m0 + lm) * HID + quad * 8);

  float4v acc[4];
#pragma unroll
  for (int nt = 0; nt < 4; ++nt) acc[nt] = (float4v){0.f, 0.f, 0.f, 0.f};

#pragma unroll
  for (int kk = 0; kk < 4; ++kk) {                // K = 4 x 32
    short8 a = ga[kk * 4];                        // kk*32 shorts = 4 short8
#pragma unroll
    for (int nt = 0; nt < 4; ++nt) {
      short8 b = *(const short8*)&W2t[(size_t)(nt * 16 + lm) * HID + kk * 32 + quad * 8];
      acc[nt] = __builtin_amdgcn_mfma_f32_16x16x32_bf16(a, b, acc[nt], 0, 0, 0);
    }
  }

#pragma unroll
  for (int nt = 0; nt < 4; ++nt) {
#pragma unroll
    for (int r = 0; r < 4; ++r) {
      int row = m0 + quad * 4 + r;
      h2bf[(size_t)row * OUT_F + nt * 16 + lm] = f2bf(acc[nt][r]);
    }
  }

  // ---- fused att2: single head over 64 cols ----
  float as0 = att_src[lm], as1v = att_src[16 + lm], as2v = att_src[32 + lm], as3 = att_src[48 + lm];
  float ad0 = att_dst[lm], ad1v = att_dst[16 + lm], ad2v = att_dst[32 + lm], ad3 = att_dst[48 + lm];
#pragma unroll
  for (int r = 0; r < 4; ++r) {
    int row = m0 + quad * 4 + r;
    float s = acc[0][r] * as0 + acc[1][r] * as1v + acc[2][r] * as2v + acc[3][r] * as3;
    float d = acc[0][r] * ad0 + acc[1][r] * ad1v + acc[2][r] * ad2v + acc[3][r] * ad3;
#pragma unroll
    for (int m = 1; m < 16; m <<= 1) { s += __shfl_xor(s, m); d += __shfl_xor(d, m); }
    if (lm == 0) { a_s[row] = s; a_d[row] = d; }
  }
}

// ---------------- CSR construction (dst-range partitioned; v7 revert) -----------
// R6 single-pass scatter: 16x write amplification (WRITE_SIZE 55 MB for 3.4 MB
// payload, 62 us) from cross-XCD line bouncing on random 4B stores. The range
// partition (g = bid&7) pins each group to one XCD (round-robin dispatch) AND
// confines its writes to a contiguous 1/8 slice -> lines fill within one L2.
__global__ __launch_bounds__(256) void deg_part_kernel(const int* __restrict__ ei,
                                                       int* __restrict__ deg) {
  const int g = blockIdx.x & (NRANGE - 1);
  const int tg = (blockIdx.x >> 3) * 256 + threadIdx.x;   // thread idx in group
  const int lo = g * RSPAN, hi = lo + RSPAN;
  for (int e = tg; e < ET; e += BPG * 256) {
    int d = (e < E_EDGES) ? ei[E_EDGES + e] : (e - E_EDGES);
    if (d >= lo && d < hi) atomicAdd(&deg[d], 1);
  }
}

__global__ __launch_bounds__(256) void scatter_part_kernel(const int* __restrict__ ei,
                                                           int* __restrict__ cursor,
                                                           int* __restrict__ csr_src) {
  const int g = blockIdx.x & (NRANGE - 1);
  const int tg = (blockIdx.x >> 3) * 256 + threadIdx.x;
  const int lo = g * RSPAN, hi = lo + RSPAN;
  for (int e = tg; e < ET; e += BPG * 256) {
    int d = (e < E_EDGES) ? ei[E_EDGES + e] : (e - E_EDGES);
    if (d >= lo && d < hi) {
      int s = (e < E_EDGES) ? ei[e] : d;
      int pos = atomicAdd(&cursor[d], 1);
      csr_src[pos] = s;
    }
  }
}

__global__ __launch_bounds__(256) void scan1_kernel(const int* __restrict__ deg,
                                                    int* __restrict__ exq,
                                                    int* __restrict__ bsum) {
  __shared__ int sh[256];
  const int t = threadIdx.x;
  const int idx = blockIdx.x * 256 + t;
  int v = (idx < N_NODES) ? deg[idx] : 0;
  sh[t] = v;
  __syncthreads();
  for (int off = 1; off < 256; off <<= 1) {
    int u = (t >= off) ? sh[t - off] : 0;
    __syncthreads();
    sh[t] += u;
    __syncthreads();
  }
  if (idx < N_NODES) exq[idx] = sh[t] - v;
  if (t == 255) bsum[blockIdx.x] = sh[t];
}

// v7: scan2 folded in — every block redundantly prefix-sums the 196 bsum
// entries in LDS (trivial) and picks its own offset; one fewer dispatch.
__global__ __launch_bounds__(256) void scan3_kernel(const int* __restrict__ exq,
                                                    const int* __restrict__ bsum,
                                                    int* __restrict__ rowptr,
                                                    int* __restrict__ cursor) {
  __shared__ int sh[256];
  const int t = threadIdx.x;
  int v = (t < NBLK) ? bsum[t] : 0;
  sh[t] = v;
  __syncthreads();
  for (int off = 1; off < 256; off <<= 1) {
    int u = (t >= off) ? sh[t - off] : 0;
    __syncthreads();
    sh[t] += u;
    __syncthreads();
  }
  const int boff = (blockIdx.x == 0) ? 0 : sh[blockIdx.x - 1];
  const int idx = blockIdx.x * 256 + t;
  if (idx < N_NODES) {
    int r = exq[idx] + boff;
    rowptr[idx] = r;
    cursor[idx] = r;
  }
  if (idx == 0) rowptr[N_NODES] = ET;
}

// ---------------- agg1: wave/dst; 16-lane×16B row gathers (4 edges/instr) -------
// v4: one vector load prefetches the whole neighbor list (lane l holds
// csr_src[start+l], clamped); per-round indices via __shfl. Rounds unrolled with
// wave-uniform deg guards so all gathers of a wave issue back-to-back.
__global__ __launch_bounds__(256) void agg1_csr_kernel(const int* __restrict__ rowptr,
                                                       const int* __restrict__ csr_src,
                                                       const float* __restrict__ a_s,
                                                       const float* __restrict__ a_d,
                                                       const unsigned short* __restrict__ h1bf,
                                                       const float* __restrict__ b1,
                                                       unsigned short* __restrict__ out1bf) {
  int wid = (blockIdx.x * 256 + threadIdx.x) >> 6;
  int lane = threadIdx.x & 63;
  if (wid >= N_NODES) return;
  const int fl = lane & 15;
  const int g  = lane >> 4;
  const int myh = fl >> 1;
  const float adn = a_d[(unsigned)(wid * HEADS1 + myh)];
  const int start = rowptr[wid], end = rowptr[wid + 1];
  const int deg = end - start;                 // >= 1 (self loop)
  // prefetch up to 64 edge indices, one per lane (clamped to start = valid node)
  int el = start + lane;
  int sall = csr_src[el < end ? el : start];
  float2v acc2[4];                  // feats fl*8 + {2d, 2d+1}
#pragma unroll
  for (int d = 0; d < 4; ++d) acc2[d] = (float2v){0.f, 0.f};
  float wsum = 0.f;

#define AGG1_ROUND(t)                                                          \
  {                                                                            \
    int i0 = 8 * (t) + g, i1 = 8 * (t) + 4 + g;                                \
    int s0 = __shfl(sall, i0);                                                 \
    int s1 = __shfl(sall, i1);                                                 \
    bool v0 = i0 < deg, v1 = i1 < deg;                                         \
    float l0 = a_s[(unsigned)(s0 * HEADS1 + myh)];                             \
    float l1 = a_s[(unsigned)(s1 * HEADS1 + myh)];                             \
    uint4 r0 = *(const uint4*)&h1bf[(unsigned)(s0 * HID + fl * 8)];            \
    uint4 r1 = *(const uint4*)&h1bf[(unsigned)(s1 * HID + fl * 8)];            \
    float w0 = v0 ? __expf(lrelu(l0 + adn)) : 0.f;                             \
    float w1 = v1 ? __expf(lrelu(l1 + adn)) : 0.f;                             \
    float2v w0v = {w0, w0}, w1v = {w1, w1};                                    \
    acc2[0] += w0v * unpk2(r0.x);  acc2[0] += w1v * unpk2(r1.x);               \
    acc2[1] += w0v * unpk2(r0.y);  acc2[1] += w1v * unpk2(r1.y);               \
    acc2[2] += w0v * unpk2(r0.z);  acc2[2] += w1v * unpk2(r1.z);               \
    acc2[3] += w0v * unpk2(r0.w);  acc2[3] += w1v * unpk2(r1.w);               \
    wsum += w0 + w1;                                                           \
  }

  AGG1_ROUND(0)
  AGG1_ROUND(1)
  if (deg > 16) {                      // wave-uniform branch
    AGG1_ROUND(2)
    AGG1_ROUND(3)
  }
#undef AGG1_ROUND
  if (deg > 32) {                      // rare tail (P[deg>32] ~ 1e-4)
    for (int i = start + 32; i < end; i += 8) {
      int e0 = i + g, e1 = i + 4 + g;
      bool v0 = e0 < end, v1 = e1 < end;
      int s0 = csr_src[v0 ? e0 : start];
      int s1 = csr_src[v1 ? e1 : start];
      float l0 = a_s[(unsigned)(s0 * HEADS1 + myh)];
      float l1 = a_s[(unsigned)(s1 * HEADS1 + myh)];
      uint4 r0 = *(const uint4*)&h1bf[(unsigned)(s0 * HID + fl * 8)];
      uint4 r1 = *(const uint4*)&h1bf[(unsigned)(s1 * HID + fl * 8)];
      float w0 = v0 ? __expf(lrelu(l0 + adn)) : 0.f;
      float w1 = v1 ? __expf(lrelu(l1 + adn)) : 0.f;
      float2v w0v = {w0, w0}, w1v = {w1, w1};
      acc2[0] += w0v * unpk2(r0.x);  acc2[0] += w1v * unpk2(r1.x);
      acc2[1] += w0v * unpk2(r0.y);  acc2[1] += w1v * unpk2(r1.y);
      acc2[2] += w0v * unpk2(r0.z);  acc2[2] += w1v * unpk2(r1.z);
      acc2[3] += w0v * unpk2(r0.w);  acc2[3] += w1v * unpk2(r1.w);
      wsum += w0 + w1;
    }
  }

#pragma unroll
  for (int d = 0; d < 4; ++d) {
    float ax = acc2[d].x, ay = acc2[d].y;
    ax += __shfl_xor(ax, 16); ax += __shfl_xor(ax, 32);
    ay += __shfl_xor(ay, 16); ay += __shfl_xor(ay, 32);
    acc2[d].x = ax; acc2[d].y = ay;
  }
  wsum += __shfl_xor(wsum, 16);
  wsum += __shfl_xor(wsum, 32);

  // ---- distributed epilogue: lane (fl,g) finalizes feats fl*8+g*2 .. +1 ----
  float inv = 1.f / (wsum + 1e-16f);
  float2v ee = (g & 2) ? ((g & 1) ? acc2[3] : acc2[2]) : ((g & 1) ? acc2[1] : acc2[0]);
  float2 bb = *(const float2*)&b1[fl * 8 + g * 2];
  float v0 = ee.x * inv + bb.x;
  float v1 = ee.y * inv + bb.y;
  v0 = v0 > 0.f ? v0 : __expf(v0) - 1.f;   // ELU; bf16-quantized below
  v1 = v1 > 0.f ? v1 : __expf(v1) - 1.f;
  unsigned pk = (unsigned)f2bf(v0) | ((unsigned)f2bf(v1) << 16);
  ((unsigned*)&out1bf[(size_t)wid * HID])[fl * 4 + g] = pk;   // 64-lane 256B row
}

// ---------------- agg2: wave/dst; 8-lane×16B row gathers (8 edges/instr) --------
__global__ __launch_bounds__(256) void agg2_csr_kernel(const int* __restrict__ rowptr,
                                                       const int* __restrict__ csr_src,
                                                       const float* __restrict__ a_s,
                                                       const float* __restrict__ a_d,
                                                       const unsigned short* __restrict__ h2bf,
                                                       const float* __restrict__ b2,
                                                       float* __restrict__ out) {
  int wid = (blockIdx.x * 256 + threadIdx.x) >> 6;
  int lane = threadIdx.x & 63;
  if (wid >= N_NODES) return;
  const int fl = lane & 7;       // owns feats [8*fl, 8*fl+8)
  const int g  = lane >> 3;      // edge group 0..7
  const float adn = a_d[wid];
  const int start = rowptr[wid], end = rowptr[wid + 1];
  const int deg = end - start;
  int el = start + lane;
  int sall = csr_src[el < end ? el : start];
  float2v acc2[4];               // feats fl*8 + {2d, 2d+1}
#pragma unroll
  for (int d = 0; d < 4; ++d) acc2[d] = (float2v){0.f, 0.f};
  float wsum = 0.f;

#define AGG2_ROUND(t)                                                          \
  {                                                                            \
    int i0 = 16 * (t) + g, i1 = 16 * (t) + 8 + g;                              \
    int s0 = __shfl(sall, i0);                                                 \
    int s1 = __shfl(sall, i1);                                                 \
    bool v0 = i0 < deg, v1 = i1 < deg;                                         \
    float l0 = a_s[s0];                                                        \
    float l1 = a_s[s1];                                                        \
    uint4 r0 = *(const uint4*)&h2bf[(unsigned)(s0 * OUT_F + fl * 8)];          \
    uint4 r1 = *(const uint4*)&h2bf[(unsigned)(s1 * OUT_F + fl * 8)];          \
    float w0 = v0 ? __expf(lrelu(l0 + adn)) : 0.f;                             \
    float w1 = v1 ? __expf(lrelu(l1 + adn)) : 0.f;                             \
    float2v w0v = {w0, w0}, w1v = {w1, w1};                                    \
    acc2[0] += w0v * unpk2(r0.x);  acc2[0] += w1v * unpk2(r1.x);               \
    acc2[1] += w0v * unpk2(r0.y);  acc2[1] += w1v * unpk2(r1.y);               \
    acc2[2] += w0v * unpk2(r0.z);  acc2[2] += w1v * unpk2(r1.z);               \
    acc2[3] += w0v * unpk2(r0.w);  acc2[3] += w1v * unpk2(r1.w);               \
    wsum += w0 + w1;                                                           \
  }

  AGG2_ROUND(0)
  if (deg > 16) {                      // wave-uniform branch
    AGG2_ROUND(1)
  }
#undef AGG2_ROUND
  if (deg > 32) {                      // rare tail
    for (int i = start + 32; i < end; i += 16) {
      int e0 = i + g, e1 = i + 8 + g;
      bool v0 = e0 < end, v1 = e1 < end;
      int s0 = csr_src[v0 ? e0 : start];
      int s1 = csr_src[v1 ? e1 : start];
      float l0 = a_s[s0];
      float l1 = a_s[s1];
      uint4 r0 = *(const uint4*)&h2bf[(unsigned)(s0 * OUT_F + fl * 8)];
      uint4 r1 = *(const uint4*)&h2bf[(unsigned)(s1 * OUT_F + fl * 8)];
      float w0 = v0 ? __expf(lrelu(l0 + adn)) : 0.f;
      float w1 = v1 ? __expf(lrelu(l1 + adn)) : 0.f;
      float2v w0v = {w0, w0}, w1v = {w1, w1};
      acc2[0] += w0v * unpk2(r0.x);  acc2[0] += w1v * unpk2(r1.x);
      acc2[1] += w0v * unpk2(r0.y);  acc2[1] += w1v * unpk2(r1.y);
      acc2[2] += w0v * unpk2(r0.z);  acc2[2] += w1v * unpk2(r1.z);
      acc2[3] += w0v * unpk2(r0.w);  acc2[3] += w1v * unpk2(r1.w);
      wsum += w0 + w1;
    }
  }

#pragma unroll
  for (int d = 0; d < 4; ++d) {
    float ax = acc2[d].x, ay = acc2[d].y;
    ax += __shfl_xor(ax, 8); ax += __shfl_xor(ax, 16); ax += __shfl_xor(ax, 32);
    ay += __shfl_xor(ay, 8); ay += __shfl_xor(ay, 16); ay += __shfl_xor(ay, 32);
    acc2[d].x = ax; acc2[d].y = ay;
  }
  wsum += __shfl_xor(wsum, 8);
  wsum += __shfl_xor(wsum, 16);
  wsum += __shfl_xor(wsum, 32);

  float inv = 1.f / (wsum + 1e-16f);
  float4 blo = *(const float4*)&b2[fl * 8];
  float4 bhi = *(const float4*)&b2[fl * 8 + 4];
  float vv[8];
  vv[0] = acc2[0].x * inv + blo.x; vv[1] = acc2[0].y * inv + blo.y;
  vv[2] = acc2[1].x * inv + blo.z; vv[3] = acc2[1].y * inv + blo.w;
  vv[4] = acc2[2].x * inv + bhi.x; vv[5] = acc2[2].y * inv + bhi.y;
  vv[6] = acc2[3].x * inv + bhi.z; vv[7] = acc2[3].y * inv + bhi.w;
  float m = vv[0];
#pragma unroll
  for (int k = 1; k < 8; ++k) m = fmaxf(m, vv[k]);
#pragma unroll
  for (int msk = 1; msk < 8; msk <<= 1) m = fmaxf(m, __shfl_xor(m, msk));
  float sm = 0.f;
#pragma unroll
  for (int k = 0; k < 8; ++k) sm += __expf(vv[k] - m);
#pragma unroll
  for (int msk = 1; msk < 8; msk <<= 1) sm += __shfl_xor(sm, msk);
  float lse = m + __logf(sm);
  if (g == 0) {
    float4 o0 = make_float4(vv[0] - lse, vv[1] - lse, vv[2] - lse, vv[3] - lse);
    float4 o1 = make_float4(vv[4] - lse, vv[5] - lse, vv[6] - lse, vv[7] - lse);
    *(float4*)&out[(size_t)wid * OUT_F + fl * 8]     = o0;
    *(float4*)&out[(size_t)wid * OUT_F + fl * 8 + 4] = o1;
  }
}

extern "C" void kernel_launch(void* const* d_in, const int* in_sizes, int n_in,
                              void* d_out, int out_size, void* d_ws, size_t ws_size,
                              hipStream_t stream) {
  const float* x   = (const float*)d_in[0];
  const int* ei    = (const int*)d_in[1];
  const float* W1  = (const float*)d_in[2];
  const float* as1 = (const float*)d_in[3];
  const float* ad1 = (const float*)d_in[4];
  const float* b1  = (const float*)d_in[5];
  const float* W2  = (const float*)d_in[6];
  const float* as2 = (const float*)d_in[7];
  const float* ad2 = (const float*)d_in[8];
  const float* b2  = (const float*)d_in[9];
  float* out = (float*)d_out;

  float* ws = (float*)d_ws;
  float* a_s1   = ws;  ws += (size_t)N_NODES * HEADS1;
  float* a_d1   = ws;  ws += (size_t)N_NODES * HEADS1;
  float* a_s2   = ws;  ws += (size_t)N_NODES;
  float* a_d2   = ws;  ws += (size_t)N_NODES;
  unsigned short* h1bf   = (unsigned short*)ws;  ws += (size_t)N_NODES * HID / 2;
  unsigned short* out1bf = (unsigned short*)ws;  ws += (size_t)N_NODES * HID / 2;
  unsigned short* h2bf   = (unsigned short*)ws;  ws += (size_t)N_NODES * OUT_F / 2;
  unsigned short* W1t = (unsigned short*)ws;  ws += (IN_F * HID) / 2;
  unsigned short* W2t = (unsigned short*)ws;  ws += (HID * OUT_F) / 2;
  int* deg      = (int*)ws;  ws += (N_NODES + 1);
  int* rowptr   = (int*)ws;  ws += (N_NODES + 1);
  int* cursor   = (int*)ws;  ws += N_NODES;
  int* csr_src  = (int*)ws;  ws += ET;
  int* exq      = (int*)ws;  ws += N_NODES;
  int* bsum     = (int*)ws;  ws += NBLK;
  int* boff     = (int*)ws;  ws += NBLK;

  // ---- weight transpose+cast + deg zero-init (one dispatch) ----
  wt_deg_kernel<<<dim3(NBLK), dim3(256), 0, stream>>>(W1, W2, W1t, W2t, deg);

  // ---- CSR build (dst-range partitioned; XCD-affine groups) ----
  deg_part_kernel<<<dim3(NRANGE * BPG), dim3(256), 0, stream>>>(ei, deg);
  scan1_kernel<<<dim3(NBLK), dim3(256), 0, stream>>>(deg, exq, bsum);
  scan3_kernel<<<dim3(NBLK), dim3(256), 0, stream>>>(exq, bsum, rowptr, cursor);
  scatter_part_kernel<<<dim3(NRANGE * BPG), dim3(256), 0, stream>>>(ei, cursor, csr_src);

  // ---- layer 1 ----
  gemm1_mfma_kernel<<<dim3(1568), dim3(256), 0, stream>>>(x, W1t, as1, ad1, h1bf, a_s1, a_d1);
  agg1_csr_kernel<<<dim3((N_NODES + 3) / 4), dim3(256), 0, stream>>>(rowptr, csr_src, a_s1, a_d1, h1bf, b1, out1bf);

  // ---- layer 2 ----
  gemm2_mfma_kernel<<<dim3((N_NODES + 63) / 64), dim3(256), 0, stream>>>(out1bf, W2t, as2, ad2, h2bf, a_s2, a_d2);
  agg2_csr_kernel<<<dim3((N_NODES + 3) / 4), dim3(256), 0, stream>>>(rowptr, csr_src, a_s2, a_d2, h2bf, b2, out);
}